// Round 12
// baseline (4858.730 us; speedup 1.0000x reference)
//
#include <hip/hip_runtime.h>
#include <cstdint>

// ---------------------------------------------------------------------------
// Threefry-2x32 (JAX partitionable-mode compatible), host + device.
// ---------------------------------------------------------------------------
__host__ __device__ inline uint32_t tf_rotl32(uint32_t x, uint32_t r) {
  return (x << r) | (x >> (32u - r));
}

__host__ __device__ inline void threefry2x32(uint32_t k0, uint32_t k1,
                                             uint32_t x0, uint32_t x1,
                                             uint32_t* o0, uint32_t* o1) {
  uint32_t ks0 = k0, ks1 = k1, ks2 = k0 ^ k1 ^ 0x1BD11BDAu;
  x0 += ks0; x1 += ks1;
#define TF_R(r) { x0 += x1; x1 = tf_rotl32(x1, r); x1 ^= x0; }
  TF_R(13) TF_R(15) TF_R(26) TF_R(6)
  x0 += ks1; x1 += ks2 + 1u;
  TF_R(17) TF_R(29) TF_R(16) TF_R(24)
  x0 += ks2; x1 += ks0 + 2u;
  TF_R(13) TF_R(15) TF_R(26) TF_R(6)
  x0 += ks0; x1 += ks1 + 3u;
  TF_R(17) TF_R(29) TF_R(16) TF_R(24)
  x0 += ks1; x1 += ks2 + 4u;
  TF_R(13) TF_R(15) TF_R(26) TF_R(6)
  x0 += ks2; x1 += ks0 + 5u;
#undef TF_R
  *o0 = x0; *o1 = x1;
}

// ---------------------------------------------------------------------------
// Problem dims
// ---------------------------------------------------------------------------
#define BSZ   8192
#define KIN   784
#define HID   800
#define NOUT  10
#define NSTEP 25

// R8: golden = Eigen gebp (AVX no-FMA jaxlib): k-panels [0,264) [264,528)
// [528,784), per k-step acc = rn(acc + rn(a*b)); C = 0.5*rn(rn(P0+P1)+P2).
// R9: a in {0,1,2} makes every product exact, so fmaf == mul+add bit-exactly.
// R17: panel-split grid x3 -> occ 72%, gemm 158us (best).
// R20 null result: killing the staging stream (gload_lds, VGPR 48->24,
//   LDS est 147->122us) left the wall EXACTLY at 158.8us. Both pipes ~77%.
//   -> dependency-stall bound. Culprit: VGPR=24 — only ~1 ds_read_b128 can
//   be in flight; compiler serialized the 10 per-tile LDS reads.
// R21 (this round): explicit full-tile register prefetch — A (2x uint4) +
//   B (float4 bq[8], compile-time indexed) loaded before the kk loop.
//   10 independent ds_reads -> 1 wait -> pure-VALU stream. Forces ~64 VGPR,
//   restores LDS ILP, extends cover for tile t+1's gload_lds drain.
//   Bit-exact (pure scheduling). Predict gemm 158.8 -> 125-145; falsifier:
//   VGPR up but dur flat -> barrier/drain-structure bound (2 tiles/barrier
//   next).
// ---------------------------------------------------------------------------

// ---------------------------------------------------------------------------
// Kernel 1: Poisson encoding (JAX-faithful: truncated 2^-23 grid).
// enc = temp + 1 in {0,1,2}; sp = 0.5*enc (exact power-of-2 relation).
// ---------------------------------------------------------------------------
__global__ __launch_bounds__(256) void enc_kernel(const float* __restrict__ inp,
                                                  uint8_t* __restrict__ enc,
                                                  uint32_t k0, uint32_t k1) {
  int j = blockIdx.x * blockDim.x + threadIdx.x;
  if (j >= BSZ * KIN) return;
  uint32_t o0, o1;
  threefry2x32(k0, k1, 0u, (uint32_t)j, &o0, &o1);
  uint32_t bits = o0 ^ o1;
  float r = __uint_as_float((bits >> 9) | 0x3f800000u) - 1.0f;
  float x = inp[j];
  bool cond = (2.0f * r <= fabsf(x));
  int s = (x > 0.0f) ? 1 : ((x < 0.0f) ? -1 : 0);
  enc[j] = (uint8_t)(1 + (cond ? s : 0));
}

// ---------------------------------------------------------------------------
// Kernel 2: panel partial Pz[b,j] for panel z = blockIdx.z.
// BM=128, BN=32, BK=8. 256 threads (4 waves), 4x4 acc per thread.
// As: u8 row-major [2][128 rows][8 k] staged by wave0 via global_load_lds.
// Bs: f32 [2][BK][BN] staged by wave1 via global_load_lds with per-lane
// pre-permuted source addresses (transpose-by-address, LDS stays linear).
// Inner per tile/thread: register-prefetch 2x b128 (A) + 8x b128 (B), one
// lgkm wait, then per kk: 4 cvt + 8 pk_fma (pure VALU).
// ---------------------------------------------------------------------------
#define BM 128
#define BN 32
#define BK 8

typedef float f32x2 __attribute__((ext_vector_type(2)));
typedef uint32_t u32;

__device__ __forceinline__ float cvt_ub(u32 x, int i) {
  return (float)((x >> (8 * i)) & 0xffu);   // folds to v_cvt_f32_ubyte_i
}

// async global->LDS, 4B/lane: LDS dest = base + lane*4; source per-lane.
__device__ __forceinline__ void gload4(const void* g, void* l) {
  __builtin_amdgcn_global_load_lds(
      (const __attribute__((address_space(1))) void*)g,
      (__attribute__((address_space(3))) void*)l, 4, 0, 0);
}

// acc.lo = fma(a.lo, b.lo, acc.lo); acc.hi = fma(a.lo, b.hi, acc.hi)
// Per-half rounding == v_fma_f32 (bit-exact); src0 half broadcast via op_sel.
__device__ __forceinline__ void pk_fma_lo(f32x2& acc, f32x2 a, f32x2 b) {
  asm("v_pk_fma_f32 %0, %1, %2, %0 op_sel:[0,0,0] op_sel_hi:[0,1,1]"
      : "+v"(acc)
      : "v"(a), "v"(b));
}
// same but broadcasting src0.hi
__device__ __forceinline__ void pk_fma_hi(f32x2& acc, f32x2 a, f32x2 b) {
  asm("v_pk_fma_f32 %0, %1, %2, %0 op_sel:[1,0,0] op_sel_hi:[1,1,1]"
      : "+v"(acc)
      : "v"(a), "v"(b));
}

__global__ __launch_bounds__(256) void gemm_kernel(const uint8_t* __restrict__ enc,
                                                   const float* __restrict__ w1,
                                                   float* __restrict__ gp) {
  __shared__ u32   As[2][BK * BM / 4];  // 2 x 1 KB; flat word 2r+h = row r, k 4h..4h+3
  __shared__ float Bs[2][BK][BN];       // 2 x 1 KB
  const int panel  = blockIdx.z;
  const int kstart = panel * 264;
  const int ntile  = (panel == 2) ? 32 : 33;
  const int m0 = blockIdx.x * BM;
  const int n0 = blockIdx.y * BN;
  const int t  = threadIdx.x;
  const int lane = t & 63;
  const int wv   = t >> 6;

  // compute mapping: 32 row-groups x 8 col-groups, 4x4 per thread
  const int tm = t / 8;        // 0..31 -> rows tm*4 .. +3
  const int tn = t % 8;        // 0..7  -> cols tn*4 .. +3

  // per-lane staging source bases (k-offset 0 of this panel)
  // A instr q, lane i -> LDS word 64q+i = row 32q+(i>>1), bytes (i&1)*4..+3
  const uint8_t* a_src = enc + (size_t)(m0 + (lane >> 1)) * KIN + kstart + (lane & 1) * 4;
  // B instr q, lane i -> LDS word 64q+i = Bs[2q+(i>>5)][i&31]
  const float*   b_src = w1  + (size_t)(n0 + (lane & 31)) * KIN + kstart + (lane >> 5);

  f32x2 acc[4][2];   // single panel chain: [mi][nj] covers cols 2nj,2nj+1
#pragma unroll
  for (int mi = 0; mi < 4; mi++)
#pragma unroll
    for (int nj = 0; nj < 2; nj++) acc[mi][nj] = (f32x2)(0.0f);

#define ISSUE(P, TILE)                                                    \
  {                                                                       \
    if (wv == 0) {                                                        \
      _Pragma("unroll")                                                   \
      for (int q = 0; q < 4; q++)                                         \
        gload4(a_src + (size_t)(TILE) * BK + (size_t)(32 * q) * KIN,      \
               &As[P][64 * q]);                                           \
    } else if (wv == 1) {                                                 \
      _Pragma("unroll")                                                   \
      for (int q = 0; q < 4; q++)                                         \
        gload4(b_src + (size_t)(TILE) * BK + 2 * q, &Bs[P][2 * q][0]);    \
    }                                                                     \
  }

  // ---- prologue: stage tile 0 into buffer 0 ----
  ISSUE(0, 0)
  __syncthreads();   // issuing waves drain vmcnt before signaling

  int p = 0;
  for (int tile = 0; tile < ntile; tile++) {
    // issue next tile into the other buffer; lands while we compute
    if (tile + 1 < ntile) { ISSUE(p ^ 1, tile + 1) }
    // ---- register-prefetch the WHOLE tile: 10 independent ds_reads ----
    const u32* aw = &As[p][tm * 8];
    uint4 qa = *(const uint4*)(aw);      // rows 4tm, 4tm+1 (k0-3, k4-7 each)
    uint4 qb = *(const uint4*)(aw + 4);  // rows 4tm+2, 4tm+3
    float4 bq[8];                        // all 8 kk B-quads, forced live
#pragma unroll
    for (int kk = 0; kk < BK; kk++)
      bq[kk] = *(const float4*)&Bs[p][kk][tn * 4];
    // ---- pure-VALU FMA stream (ascending-k chain) ----
#pragma unroll
    for (int kk = 0; kk < BK; kk++) {
      const u32 w0  = (kk < 4) ? qa.x : qa.y;   // row 4tm
      const u32 w1r = (kk < 4) ? qa.z : qa.w;   // row 4tm+1
      const u32 w2  = (kk < 4) ? qb.x : qb.y;   // row 4tm+2
      const u32 w3  = (kk < 4) ? qb.z : qb.w;   // row 4tm+3
      const int sh = kk & 3;
      f32x2 am[2];
      am[0].x = cvt_ub(w0, sh);  am[0].y = cvt_ub(w1r, sh);
      am[1].x = cvt_ub(w2, sh);  am[1].y = cvt_ub(w3, sh);
      f32x2 b2[2];
      b2[0].x = bq[kk].x; b2[0].y = bq[kk].y;
      b2[1].x = bq[kk].z; b2[1].y = bq[kk].w;
      // rows: mi = 2*mp + h (h = broadcast half of am[mp])
#pragma unroll
      for (int mp = 0; mp < 2; mp++) {
        pk_fma_lo(acc[2 * mp + 0][0], am[mp], b2[0]);
        pk_fma_lo(acc[2 * mp + 0][1], am[mp], b2[1]);
        pk_fma_hi(acc[2 * mp + 1][0], am[mp], b2[0]);
        pk_fma_hi(acc[2 * mp + 1][1], am[mp], b2[1]);
      }
    }
    __syncthreads();   // everyone done reading p; next-tile loads landed
    p ^= 1;
  }
#undef ISSUE

  // epilogue: write RAW panel partial (combine happens in update_kernel)
  float* base = gp + (size_t)panel * BSZ * HID;
#pragma unroll
  for (int mi = 0; mi < 4; mi++) {
    float* dst = base + (size_t)(m0 + tm * 4 + mi) * HID + n0 + tn * 4;
    float4 o;
    o.x = acc[mi][0].x;
    o.y = acc[mi][0].y;
    o.z = acc[mi][1].x;
    o.w = acc[mi][1].y;
    *(float4*)dst = o;
  }
}

// ---------------------------------------------------------------------------
// Kernel 3: combine panels (exact Eigen order) + membrane update + spike +
// mem2 accumulation.
// g = 0.5 * rn(rn(P0+P1) + P2)   (0.5 exact)
// m = rn(rn(0.95f*mem) + rn(0.05f*g)) — mul/mul/add; products NOT exact here,
// so FMA contraction would change bits — keep split __fmul_rn/__fadd_rn.
// ---------------------------------------------------------------------------
__global__ __launch_bounds__(256) void update_kernel(const float* __restrict__ gp,
                                                     float* __restrict__ mem1,
                                                     const float* __restrict__ w2,
                                                     float* __restrict__ mem2) {
  __shared__ float w2s[NOUT * HID];   // 32 KB
  for (int i = threadIdx.x; i < NOUT * HID; i += 256) w2s[i] = w2[i];
  __syncthreads();

  const int wave = threadIdx.x / 64;
  const int lane = threadIdx.x % 64;
  const int b = blockIdx.x * 4 + wave;

  const size_t GS = (size_t)BSZ * HID;
  const float* g0 = gp + (size_t)b * HID;
  const float* g1 = g0 + GS;
  const float* g2 = g1 + GS;
  float* mrow = mem1 + (size_t)b * HID;

  float acc[NOUT];
#pragma unroll
  for (int i = 0; i < NOUT; i++) acc[i] = 0.0f;

  for (int j = lane; j < HID; j += 64) {
    float gs = __fmul_rn(0.5f, __fadd_rn(__fadd_rn(g0[j], g1[j]), g2[j]));
    float m = __fadd_rn(__fmul_rn(0.95f, mrow[j]), __fmul_rn(0.05f, gs));
    bool spike = __fadd_rn(m, -1.0f) > 0.0f;
    mrow[j] = spike ? __fadd_rn(m, -1.0f) : m;
    if (spike) {
#pragma unroll
      for (int i = 0; i < NOUT; i++) acc[i] += w2s[i * HID + j];
    }
  }
  // mem2 never feeds back into spike decisions: reduction-order noise ~1e-7
  // << 3.6e-3 threshold, no need to replicate ref's order here.
#pragma unroll
  for (int i = 0; i < NOUT; i++) {
    float v = acc[i];
    for (int off = 32; off > 0; off >>= 1) v += __shfl_down(v, off);
    if (lane == 0) mem2[(size_t)b * NOUT + i] += v;
  }
}

// ---------------------------------------------------------------------------
// Kernel 4: out = mem2 / num_steps
// ---------------------------------------------------------------------------
__global__ __launch_bounds__(256) void finalize_kernel(const float* __restrict__ mem2,
                                                       const int* __restrict__ ns,
                                                       float* __restrict__ out) {
  int i = blockIdx.x * blockDim.x + threadIdx.x;
  if (i < BSZ * NOUT) out[i] = mem2[i] / (float)(*ns);
}

// ---------------------------------------------------------------------------
extern "C" void kernel_launch(void* const* d_in, const int* in_sizes, int n_in,
                              void* d_out, int out_size, void* d_ws, size_t ws_size,
                              hipStream_t stream) {
  const float* inp = (const float*)d_in[0];
  const float* w1  = (const float*)d_in[1];
  const float* w2  = (const float*)d_in[2];
  const int*   dns = (const int*)d_in[3];
  float* out = (float*)d_out;

  char* ws = (char*)d_ws;
  size_t off = 0;
  uint8_t* enc = (uint8_t*)(ws + off);  off += (size_t)BSZ * KIN;          // 6.4 MB
  off = (off + 255) & ~(size_t)255;
  float* gp   = (float*)(ws + off);     off += (size_t)3 * BSZ * HID * 4;  // 78.6 MB
  float* mem1 = (float*)(ws + off);     off += (size_t)BSZ * HID * 4;      // 26.2 MB
  float* mem2 = (float*)(ws + off);     off += (size_t)BSZ * NOUT * 4;     // 0.33 MB

  (void)hipMemsetAsync(mem1, 0, (size_t)BSZ * HID * 4, stream);
  (void)hipMemsetAsync(mem2, 0, (size_t)BSZ * NOUT * 4, stream);

  // Step keys: partitionable split — key_t = threefry((0,42), (0,t)).
  uint32_t keys[NSTEP][2];
  for (int t = 0; t < NSTEP; t++)
    threefry2x32(0u, 42u, 0u, (uint32_t)t, &keys[t][0], &keys[t][1]);

  const int n_elem = BSZ * KIN;
  for (int t = 0; t < NSTEP; t++) {
    enc_kernel<<<(n_elem + 255) / 256, 256, 0, stream>>>(inp, enc, keys[t][0], keys[t][1]);
    gemm_kernel<<<dim3(BSZ / BM, HID / BN, 3), 256, 0, stream>>>(enc, w1, gp);
    update_kernel<<<BSZ / 4, 256, 0, stream>>>(gp, mem1, w2, mem2);
  }
  finalize_kernel<<<(BSZ * NOUT + 255) / 256, 256, 0, stream>>>(mem2, dns, out);
}